// Round 10
// baseline (562.911 us; speedup 1.0000x reference)
//
#include <hip/hip_runtime.h>
#include <hip/hip_bf16.h>

typedef float f32x4 __attribute__((ext_vector_type(4)));
typedef __bf16 bf16x8 __attribute__((ext_vector_type(8)));
typedef unsigned short u16x8 __attribute__((ext_vector_type(8)));

#define GN_EPS 1e-5f
#define LN_EPS 1e-5f
#define COS_EPS_F 1e-8f

__device__ __forceinline__ unsigned short f2bf(float f) {
  unsigned int u = __builtin_bit_cast(unsigned int, f);
  u += 0x7fffu + ((u >> 16) & 1u);   // round-to-nearest-even
  return (unsigned short)(u >> 16);
}

// ---------------------------------------------------------------------------
// Coalesced transpose + bf16 cast: x[b][ci][hw] f32 -> xT(+m*stride)[b][hw][ci].
// ---------------------------------------------------------------------------
__global__ void transpose_kernel(const float* __restrict__ x0,
                                 const float* __restrict__ x1,
                                 const float* __restrict__ x2,
                                 unsigned short* __restrict__ xT,
                                 unsigned int strideElems, int mBase) {
  __shared__ float lds[64][129];
  int m = mBase + (blockIdx.x >> 11);
  int bid = blockIdx.x & 2047;          // b*8 + cit*4 + hwt
  const float* x = (m == 0) ? x0 : ((m == 1) ? x1 : x2);
  unsigned short* dst = xT + (unsigned int)(m - mBase) * strideElems;

  int hwt = bid & 3, cit = (bid >> 2) & 1, b = bid >> 3;
  int hw0 = hwt * 64, ci0 = cit * 128;
  int tid = threadIdx.x;

  int hwx = tid & 63, cy0 = tid >> 6;
  const float* xb = x + (b * 256 + ci0) * 256 + hw0;
  #pragma unroll 8
  for (int p = 0; p < 32; ++p) {
    int cy = cy0 + 4 * p;
    lds[hwx][cy] = xb[cy * 256 + hwx];
  }
  __syncthreads();

  int cp = tid & 63, hy0 = tid >> 6;
  unsigned int* outp = (unsigned int*)(dst + (b * 256 + hw0) * 256 + ci0);
  #pragma unroll 4
  for (int p = 0; p < 16; ++p) {
    int hy = hy0 + 4 * p;
    float lo = lds[hy][2 * cp];
    float hi = lds[hy][2 * cp + 1];
    unsigned int w = ((unsigned int)f2bf(hi) << 16) | f2bf(lo);
    outp[hy * 128 + cp] = w;
  }
}

// ---------------------------------------------------------------------------
// Repack conv weights (all 3): W[co][ci][3][3] f32 -> wp[m][co][9][ci] bf16
// ---------------------------------------------------------------------------
__global__ void pack_kernel(const float* __restrict__ w0,
                            const float* __restrict__ w1,
                            const float* __restrict__ w2,
                            unsigned short* __restrict__ wp) {
  int m = blockIdx.y;
  const float* w = (m == 0) ? w0 : ((m == 1) ? w1 : w2);
  int idx = blockIdx.x * 256 + threadIdx.x;   // 0..589823
  int ci = idx & 255;
  int rest = idx >> 8;
  int khw = rest % 9, co = rest / 9;
  wp[m * 589824 + idx] = f2bf(w[(co * 256 + ci) * 9 + khw]);
}

// ---------------------------------------------------------------------------
// Fused Conv3x3 + bias + GroupNorm + ReLU + mean.
// Block = 1 image x 128 co (256x128), 8 waves (4M x 2N), wave tile 64x64,
// acc[4][4] = 64 VGPR -> __launch_bounds__(512,4) caps VGPR at 128 so
// TWO independent blocks co-reside per CU (LDS 49.8 KB). Independent blocks
// fill each other's non-MFMA phases (Guideline 1 — the untested lever).
// A-reuse: image slice [256px x 32ci] staged once per kc; 9 taps read it at
// shifted rows (borders -> zbuf). XOR chunk swizzle c^((row>>1)&3) on BOTH
// store-source and reads -> 2-way (free) on all frag reads.
// kc-outer/tap-inner (L2-friendly). One barrier + vmcnt(0) per tap.
// Template V: 0=real, 1=no per-tap ds_reads, 2=no MFMA (sinks), 3=no staging.
// ---------------------------------------------------------------------------
__device__ __forceinline__ void gl_lds16(const unsigned short* g, unsigned short* l) {
  __builtin_amdgcn_global_load_lds(
      (const __attribute__((address_space(1))) void*)g,
      (__attribute__((address_space(3))) void*)l, 16, 0, 0);
}

template <int V>
__launch_bounds__(512, 4)
__global__ void conv_gn_pool(const unsigned short* __restrict__ xT,
                             unsigned int xTstride,
                             const unsigned short* __restrict__ wp,
                             const float* __restrict__ cb0, const float* __restrict__ cb1,
                             const float* __restrict__ cb2,
                             const float* __restrict__ gg0, const float* __restrict__ gg1,
                             const float* __restrict__ gg2,
                             const float* __restrict__ gb0, const float* __restrict__ gb1,
                             const float* __restrict__ gb2,
                             float* __restrict__ enc, int mBase, int nkch) {
  __shared__ unsigned short As[2][8192];   // 32 KB: 2 bufs x (256 px x 32 ci)
  __shared__ unsigned short Bb[2][4096];   // 16 KB: 2 bufs x (128 co x 32 ci)
  __shared__ unsigned short zbuf[32];      // 64 B zero block
  __shared__ float gsum[8], gsq[8], pooled[128];

  int bid = blockIdx.x;
  int xcd = bid & 7, idx = bid >> 3;       // XCD-chunked: co-halves+images of a
  int nt = idx & 1;                        // m contiguous per XCD
  int r = idx >> 1;
  int mm = mBase + (r >> 5);
  int img = xcd * 32 + (r & 31);

  const float* cbias = (mm == 0) ? cb0 : ((mm == 1) ? cb1 : cb2);
  const float* gng   = (mm == 0) ? gg0 : ((mm == 1) ? gg1 : gg2);
  const float* gnb   = (mm == 0) ? gb0 : ((mm == 1) ? gb1 : gb2);

  int tid = threadIdx.x;
  int wid = tid >> 6, lane = tid & 63;
  int wr = wid >> 1, wc = wid & 1;         // 4M x 2N
  int l15 = lane & 15, l4 = lane >> 4;

  if (tid < 8) { gsum[tid] = 0.f; gsq[tid] = 0.f; }
  if (tid < 128) pooled[tid] = 0.f;
  if (tid < 32) zbuf[tid] = 0;

  const unsigned short* xb =
      xT + (unsigned int)(mm - mBase) * xTstride + (unsigned int)img * 65536u;
  const unsigned short* wpB = wp + mm * 589824 + nt * 128 * 2304;

  // ---- staging addresses (source pre-swizzled, rule 21) ----
  int rA0 = tid >> 2;                      // rows 0..127 (chunk tid&3)
  const unsigned short* aSrc0 =
      xb + rA0 * 256 + (((tid & 3) ^ ((rA0 >> 1) & 3)) * 8);
  // second half: rows 128..255 — same swizzle phase, +128*256 elements
  unsigned short* aDst0 = &As[0][0] + tid * 8;
  int sco = tid >> 2;
  const unsigned short* bSrc =
      wpB + sco * 2304 + (((tid & 3) ^ ((sco >> 1) & 3)) * 8);
  unsigned short* bDst = &Bb[0][0] + tid * 8;

  // ---- B frag offsets (ushort units) ----
  int bq4[4];
  #pragma unroll
  for (int nf = 0; nf < 4; ++nf) {
    int co = wc * 64 + nf * 16 + l15;
    bq4[nf] = co * 32 + ((l4 ^ ((co >> 1) & 3)) * 8);
  }

  f32x4 acc[4][4];
  #pragma unroll
  for (int i = 0; i < 4; ++i)
    #pragma unroll
    for (int j = 0; j < 4; ++j) acc[i][j] = (f32x4)(0.0f);

  #define LD8(P) __builtin_bit_cast(bf16x8, *(const u16x8*)(P))
  #define STAGE_A(KCN, PAR)                                                    \
    {                                                                          \
      gl_lds16(aSrc0 + (KCN) * 32, aDst0 + (PAR) * 8192);                      \
      gl_lds16(aSrc0 + 32768 + (KCN) * 32, aDst0 + 4096 + (PAR) * 8192);       \
    }
  #define STAGE_B(KCN, TAPN, PAR)                                              \
    gl_lds16(bSrc + (TAPN) * 256 + (KCN) * 32, bDst + (PAR) * 4096)

  bf16x8 afP[4], bfrP[4];                  // V1 preloads

  // ---- prologue ----
  if constexpr (V != 3) { STAGE_B(0, 0, 0); STAGE_A(0, 0); }
  asm volatile("s_waitcnt vmcnt(0)" ::: "memory");
  __builtin_amdgcn_s_barrier();

  if constexpr (V == 1) {
    #pragma unroll
    for (int nf = 0; nf < 4; ++nf) bfrP[nf] = LD8(&Bb[0][bq4[nf]]);
    #pragma unroll
    for (int mf = 0; mf < 4; ++mf) {
      int p = wr * 64 + mf * 16 + l15;
      afP[mf] = LD8(&As[0][p * 32 + ((l4 ^ ((p >> 1) & 3)) * 8)]);
    }
    asm volatile("s_waitcnt lgkmcnt(0)" ::: "memory");
    __builtin_amdgcn_sched_barrier(0);
  }

  #define TAP_BODY(ASP, BRD, DH, DW, DOA, AKCN, APAR, DOB, BKC, BTAP, BWR)     \
    {                                                                          \
      if constexpr (V != 3) {                                                  \
        if (DOB) STAGE_B(BKC, BTAP, BWR);                                      \
        if (DOA) STAGE_A(AKCN, APAR);                                          \
      }                                                                        \
      bf16x8 af[4], bfr[4];                                                    \
      if constexpr (V != 1) {                                                  \
        _Pragma("unroll")                                                      \
        for (int nf = 0; nf < 4; ++nf) bfr[nf] = LD8(&Bb[BRD][bq4[nf]]);       \
        _Pragma("unroll")                                                      \
        for (int mf = 0; mf < 4; ++mf) {                                       \
          int p = wr * 64 + mf * 16 + l15;                                     \
          int pp = p + ((DH) - 1) * 16 + ((DW) - 1);                           \
          bool ok = true;                                                      \
          if ((DH) == 0) ok = ok && ((p >> 4) >= 1);                           \
          if ((DH) == 2) ok = ok && ((p >> 4) <= 14);                          \
          if ((DW) == 0) ok = ok && ((p & 15) >= 1);                           \
          if ((DW) == 2) ok = ok && ((p & 15) <= 14);                          \
          const unsigned short* pa =                                           \
              ok ? &As[ASP][pp * 32 + ((l4 ^ ((pp >> 1) & 3)) * 8)]            \
                 : &zbuf[l4 * 8];                                              \
          af[mf] = LD8(pa);                                                    \
        }                                                                      \
        asm volatile("s_waitcnt lgkmcnt(0)" ::: "memory");                     \
        __builtin_amdgcn_sched_barrier(0);                                     \
      }                                                                        \
      if constexpr (V == 2) {                                                  \
        _Pragma("unroll")                                                      \
        for (int q = 0; q < 4; ++q) {                                          \
          asm volatile("" :: "v"(__builtin_bit_cast(f32x4, af[q])));           \
          asm volatile("" :: "v"(__builtin_bit_cast(f32x4, bfr[q])));          \
        }                                                                      \
      } else {                                                                 \
        __builtin_amdgcn_s_setprio(1);                                         \
        _Pragma("unroll")                                                      \
        for (int mf = 0; mf < 4; ++mf)                                         \
          _Pragma("unroll")                                                    \
          for (int nf = 0; nf < 4; ++nf) {                                     \
            if constexpr (V == 1)                                              \
              acc[mf][nf] = __builtin_amdgcn_mfma_f32_16x16x32_bf16(           \
                  afP[mf], bfrP[nf], acc[mf][nf], 0, 0, 0);                    \
            else                                                               \
              acc[mf][nf] = __builtin_amdgcn_mfma_f32_16x16x32_bf16(           \
                  af[mf], bfr[nf], acc[mf][nf], 0, 0, 0);                      \
          }                                                                    \
        __builtin_amdgcn_s_setprio(0);                                         \
      }                                                                        \
      asm volatile("s_waitcnt vmcnt(0)" ::: "memory");                         \
      __builtin_amdgcn_s_barrier();                                            \
    }

  for (int kch = 0; kch < nkch; ++kch) {
    int kc = kch * 2;
    // even kc: A from As[0]; B parity = tap&1
    TAP_BODY(0, 0, 0, 0, 1, kc + 1, 1, 1, kc, 1, 1)
    TAP_BODY(0, 1, 0, 1, 0, 0, 0, 1, kc, 2, 0)
    TAP_BODY(0, 0, 0, 2, 0, 0, 0, 1, kc, 3, 1)
    TAP_BODY(0, 1, 1, 0, 0, 0, 0, 1, kc, 4, 0)
    TAP_BODY(0, 0, 1, 1, 0, 0, 0, 1, kc, 5, 1)
    TAP_BODY(0, 1, 1, 2, 0, 0, 0, 1, kc, 6, 0)
    TAP_BODY(0, 0, 2, 0, 0, 0, 0, 1, kc, 7, 1)
    TAP_BODY(0, 1, 2, 1, 0, 0, 0, 1, kc, 8, 0)
    TAP_BODY(0, 0, 2, 2, 0, 0, 0, 1, kc + 1, 0, 1)
    int kco = kc + 1;
    int doA = (kco < 7);
    int doB9 = (kco < 7);
    // odd kc: A from As[1]; B parity = (tap+1)&1
    TAP_BODY(1, 1, 0, 0, doA, kco + 1, 0, 1, kco, 1, 0)
    TAP_BODY(1, 0, 0, 1, 0, 0, 0, 1, kco, 2, 1)
    TAP_BODY(1, 1, 0, 2, 0, 0, 0, 1, kco, 3, 0)
    TAP_BODY(1, 0, 1, 0, 0, 0, 0, 1, kco, 4, 1)
    TAP_BODY(1, 1, 1, 1, 0, 0, 0, 1, kco, 5, 0)
    TAP_BODY(1, 0, 1, 2, 0, 0, 0, 1, kco, 6, 1)
    TAP_BODY(1, 1, 2, 0, 0, 0, 0, 1, kco, 7, 0)
    TAP_BODY(1, 0, 2, 1, 0, 0, 0, 1, kco, 8, 1)
    TAP_BODY(1, 1, 2, 2, 0, 0, 0, doB9, kco + 1, 0, 0)
  }
  #undef TAP_BODY
  #undef STAGE_A
  #undef STAGE_B
  #undef LD8

  __syncthreads();

  // ---- epilogue: +bias, group stats (8 groups in this co-half) ----
  float bias[4], ggv[4], gbv[4];
  #pragma unroll
  for (int nf = 0; nf < 4; ++nf) {
    int co = nt * 128 + wc * 64 + nf * 16 + l15;
    bias[nf] = cbias[co]; ggv[nf] = gng[co]; gbv[nf] = gnb[co];
  }
  #pragma unroll
  for (int nf = 0; nf < 4; ++nf) {
    float s1 = 0.f, s2 = 0.f;
    #pragma unroll
    for (int mf = 0; mf < 4; ++mf)
      #pragma unroll
      for (int i = 0; i < 4; ++i) {
        float v = acc[mf][nf][i] + bias[nf];
        acc[mf][nf][i] = v;
        s1 += v; s2 += v * v;
      }
    #pragma unroll
    for (int d = 1; d < 64; d <<= 1) {
      s1 += __shfl_xor(s1, d);
      s2 += __shfl_xor(s2, d);
    }
    if (lane == 0) {
      atomicAdd(&gsum[wc * 4 + nf], s1);
      atomicAdd(&gsq[wc * 4 + nf], s2);
    }
  }
  __syncthreads();
  #pragma unroll
  for (int nf = 0; nf < 4; ++nf) {
    int g = wc * 4 + nf;
    float mean = gsum[g] * (1.f / 4096.f);
    float var = gsq[g] * (1.f / 4096.f) - mean * mean;
    float rs = rsqrtf(var + GN_EPS);
    float p = 0.f;
    #pragma unroll
    for (int mf = 0; mf < 4; ++mf)
      #pragma unroll
      for (int i = 0; i < 4; ++i) {
        float v = (acc[mf][nf][i] - mean) * rs * ggv[nf] + gbv[nf];
        p += fmaxf(v, 0.f);
      }
    p += __shfl_xor(p, 16);
    p += __shfl_xor(p, 32);
    if (lane < 16) atomicAdd(&pooled[wc * 64 + nf * 16 + l15], p);
  }
  __syncthreads();
  if (tid < 128)
    enc[mm * 65536 + img * 256 + nt * 128 + tid] = pooled[tid] * (1.f / 256.f);
}

// ---------------------------------------------------------------------------
// Projector + LN + l2norm + predictor. One block per row (768 rows).
// ---------------------------------------------------------------------------
__global__ void proj_pred(const float* __restrict__ enc,
                          const float* __restrict__ w1, const float* __restrict__ b1,
                          const float* __restrict__ w2, const float* __restrict__ b2,
                          const float* __restrict__ lng, const float* __restrict__ lnb,
                          const float* __restrict__ pw1, const float* __restrict__ pb1,
                          const float* __restrict__ pw2, const float* __restrict__ pb2,
                          float* __restrict__ proj, float* __restrict__ pred,
                          float* __restrict__ znorm) {
  __shared__ float row[256], h1[256], zz[128], p1[128], red[2];
  int r = blockIdx.x, tid = threadIdx.x;
  row[tid] = enc[r * 256 + tid];
  __syncthreads();
  float a = 0.f;
  for (int k = 0; k < 256; ++k) a += row[k] * w1[k * 256 + tid];
  h1[tid] = fmaxf(a + b1[tid], 0.f);
  __syncthreads();
  if (tid < 128) {
    a = 0.f;
    for (int k = 0; k < 256; ++k) a += h1[k] * w2[k * 128 + tid];
    zz[tid] = a + b2[tid];
  }
  __syncthreads();
  if (tid == 0) {
    float m = 0.f;
    for (int k = 0; k < 128; ++k) m += zz[k];
    m *= (1.f / 128.f);
    float v = 0.f;
    for (int k = 0; k < 128; ++k) { float d = zz[k] - m; v += d * d; }
    red[0] = m;
    red[1] = rsqrtf(v * (1.f / 128.f) + LN_EPS);
  }
  __syncthreads();
  float zval = 0.f;
  if (tid < 128) {
    zval = (zz[tid] - red[0]) * red[1] * lng[tid] + lnb[tid];
    proj[r * 128 + tid] = zval;
  }
  __syncthreads();
  if (tid < 128) zz[tid] = zval;
  __syncthreads();
  if (tid == 0) {
    float s = 0.f;
    for (int k = 0; k < 128; ++k) s += zz[k] * zz[k];
    red[0] = 1.f / fmaxf(sqrtf(s), COS_EPS_F);
  }
  __syncthreads();
  if (tid < 128) {
    znorm[r * 128 + tid] = zz[tid] * red[0];
    a = 0.f;
    for (int k = 0; k < 128; ++k) a += zz[k] * pw1[k * 128 + tid];
    p1[tid] = fmaxf(a + pb1[tid], 0.f);
  }
  __syncthreads();
  if (tid < 128) {
    a = 0.f;
    for (int k = 0; k < 128; ++k) a += p1[k] * pw2[k * 128 + tid];
    pred[r * 128 + tid] = a + pb2[tid];
  }
}

// ---------------------------------------------------------------------------
// Loss: block = (pair, k). lse(S[k,:]) - S[k,k] per row; partials to ws.
// ---------------------------------------------------------------------------
__global__ void loss_kernel(const float* __restrict__ zn, float* __restrict__ part) {
  __shared__ float zi[128], sv[256], rbuf[256];
  int blk = blockIdx.x;
  int p = blk >> 8, k = blk & 255;
  int i = (p == 2) ? 1 : 0;
  int j = (p == 0) ? 1 : 2;
  int tid = threadIdx.x;
  if (tid < 128) zi[tid] = zn[(i * 256 + k) * 128 + tid];
  __syncthreads();
  const float4* zj = (const float4*)&zn[(j * 256 + tid) * 128];
  float s = 0.f;
  #pragma unroll 8
  for (int d = 0; d < 32; ++d) {
    float4 aq = *(const float4*)&zi[d * 4];
    float4 bq = zj[d];
    s += aq.x * bq.x + aq.y * bq.y + aq.z * bq.z + aq.w * bq.w;
  }
  s *= 10.0f;
  sv[tid] = s;
  rbuf[tid] = s;
  __syncthreads();
  for (int d = 128; d > 0; d >>= 1) {
    if (tid < d) rbuf[tid] = fmaxf(rbuf[tid], rbuf[tid + d]);
    __syncthreads();
  }
  float m = rbuf[0];
  __syncthreads();
  rbuf[tid] = expf(s - m);
  __syncthreads();
  for (int d = 128; d > 0; d >>= 1) {
    if (tid < d) rbuf[tid] += rbuf[tid + d];
    __syncthreads();
  }
  if (tid == 0) part[blk] = m + logf(rbuf[0]) - sv[k];
}

__global__ void finalize_loss(const float* __restrict__ part, float* __restrict__ out) {
  __shared__ float red[256];
  int tid = threadIdx.x;
  float s = 0.f;
  for (int idx = tid; idx < 768; idx += 256) s += part[idx];
  red[tid] = s;
  __syncthreads();
  for (int d = 128; d > 0; d >>= 1) {
    if (tid < d) red[tid] += red[tid + d];
    __syncthreads();
  }
  if (tid == 0) out[0] = red[0] * (1.f / 768.f);
}

// ---------------------------------------------------------------------------
extern "C" void kernel_launch(void* const* d_in, const int* in_sizes, int n_in,
                              void* d_out, int out_size, void* d_ws, size_t ws_size,
                              hipStream_t stream) {
  const float* x[3]  = {(const float*)d_in[0], (const float*)d_in[1], (const float*)d_in[2]};
  const float* cw[3] = {(const float*)d_in[3], (const float*)d_in[7], (const float*)d_in[11]};
  const float* cb[3] = {(const float*)d_in[4], (const float*)d_in[8], (const float*)d_in[12]};
  const float* gg[3] = {(const float*)d_in[5], (const float*)d_in[9], (const float*)d_in[13]};
  const float* gb[3] = {(const float*)d_in[6], (const float*)d_in[10], (const float*)d_in[14]};
  const float* p_w1 = (const float*)d_in[15];
  const float* p_b1 = (const float*)d_in[16];
  const float* p_w2 = (const float*)d_in[17];
  const float* p_b2 = (const float*)d_in[18];
  const float* ln_g = (const float*)d_in[19];
  const float* ln_b = (const float*)d_in[20];
  const float* q_w1 = (const float*)d_in[21];
  const float* q_b1 = (const float*)d_in[22];
  const float* q_w2 = (const float*)d_in[23];
  const float* q_b2 = (const float*)d_in[24];

  float* out = (float*)d_out;
  char* ws = (char*)d_ws;

  const size_t XT_ONE = 33554432;
  bool merged = ws_size >= (3 * XT_ONE + 3538944 + 393216 + 3072 + 262144 + 512);

  size_t xt_total = merged ? 3 * XT_ONE : XT_ONE;
  unsigned short* xT  = (unsigned short*)ws;
  unsigned short* wpk = (unsigned short*)(ws + xt_total);
  float* znorm   = (float*)(ws + xt_total + 3538944);
  float* part    = (float*)(ws + xt_total + 3538944 + 393216);
  float* scratch = (float*)(ws + xt_total + 3538944 + 393216 + 3072);  // 256 KB

  float* enc  = out;              // [3][256][256]
  float* proj = out + 196608;     // [3][256][128]
  float* pred = out + 294912;     // [3][256][128]
  float* lossp = out + 393216;    // scalar

  pack_kernel<<<dim3(2304, 3), dim3(256), 0, stream>>>(cw[0], cw[1], cw[2], wpk);

  unsigned int stride = merged ? 16777216u : 0u;
  if (merged) {
    transpose_kernel<<<dim3(6144), dim3(256), 0, stream>>>(x[0], x[1], x[2], xT, stride, 0);
    conv_gn_pool<0><<<dim3(1536), dim3(512), 0, stream>>>(
        xT, stride, wpk, cb[0], cb[1], cb[2], gg[0], gg[1], gg[2],
        gb[0], gb[1], gb[2], enc, 0, 4);
  } else {
    for (int m = 0; m < 3; ++m) {
      transpose_kernel<<<dim3(2048), dim3(256), 0, stream>>>(x[0], x[1], x[2], xT, 0u, m);
      conv_gn_pool<0><<<dim3(512), dim3(512), 0, stream>>>(
          xT, 0u, wpk, cb[0], cb[1], cb[2], gg[0], gg[1], gg[2],
          gb[0], gb[1], gb[2], enc, m, 4);
    }
  }
  proj_pred<<<dim3(768), dim3(256), 0, stream>>>(enc, p_w1, p_b1, p_w2, p_b2, ln_g, ln_b,
                                                 q_w1, q_b1, q_w2, q_b2, proj, pred, znorm);
  loss_kernel<<<dim3(768), dim3(256), 0, stream>>>(znorm, part);
  finalize_loss<<<dim3(1), dim3(256), 0, stream>>>(part, lossp);

  // ---- diagnostic ablations (write scratch only; half K; 2 blocks/CU) ----
  conv_gn_pool<1><<<dim3(512), dim3(512), 0, stream>>>(
      xT, stride, wpk, cb[0], cb[1], cb[2], gg[0], gg[1], gg[2],
      gb[0], gb[1], gb[2], scratch, 0, 2);
  conv_gn_pool<2><<<dim3(512), dim3(512), 0, stream>>>(
      xT, stride, wpk, cb[0], cb[1], cb[2], gg[0], gg[1], gg[2],
      gb[0], gb[1], gb[2], scratch, 0, 2);
  conv_gn_pool<3><<<dim3(512), dim3(512), 0, stream>>>(
      xT, stride, wpk, cb[0], cb[1], cb[2], gg[0], gg[1], gg[2],
      gb[0], gb[1], gb[2], scratch, 0, 2);
}